// Round 7
// baseline (169.652 us; speedup 1.0000x reference)
//
#include <hip/hip_runtime.h>
#include <hip/hip_bf16.h>
#include <math.h>

#define NB 2
#define CIN 256
#define NPOS 4096          // 64*64
#define HID 128
#define NHEAD 4
#define DHEAD 32
#define NBH 8
#define NSPLIT 4
#define QSCALE 0.2550348676144781f   // 32^-0.5 * log2(e), folded into W_q

typedef __bf16 bf16;
typedef __attribute__((ext_vector_type(8))) __bf16 bf16x8;
typedef __attribute__((ext_vector_type(4))) __bf16 bf16x4;
typedef __attribute__((ext_vector_type(4))) float f32x4;

union B8 { bf16x8 v; bf16x4 h[2]; };

// ws layout (byte offsets), total 19,660,800 B (R0/R11 layout):
#define XT_OFF  0u            // xt  bf16 [2][4096][256]   4 MB
#define QB_OFF  4194304u      // qb  bf16 [8][4096][32]    2 MB  (W_q pre-scaled by QSCALE)
#define KB_OFF  6291456u      // kb  bf16 [8][4096][32]    2 MB
#define VT_OFF  8388608u      // vtb bf16 [8][32][4096]    2 MB  (V transposed)
#define AOP_OFF 10485760u     // aop bf16 [4][2][4096][128] 8 MB (partial O, [split][b][i][c])
#define LP_OFF  18874368u     // lp  f32  [4][8][4096]     512 KB
#define WB_OFF  19398656u     // wb  bf16 [384][256]       192 KB
#define WOB_OFF 19595264u     // wob bf16 [256][128]       64 KB

// ---------------- Kernel 0: prep — transpose x to bf16 [b][i][c]; cast weights ----------------
__global__ __launch_bounds__(256) void prep_kernel(const float* __restrict__ x,
                                                   const float* __restrict__ wqkv,
                                                   const float* __restrict__ wout,
                                                   bf16* __restrict__ xt,
                                                   bf16* __restrict__ wb,
                                                   bf16* __restrict__ wob) {
    const int t = threadIdx.x;
    if (blockIdx.y == 4) {
        int tid = blockIdx.x * 256 + t;           // 0..16383
        if (blockIdx.z == 0) {
            #pragma unroll
            for (int u = 0; u < 6; ++u) {
                int idx = tid * 6 + u;            // 98304 = 384*256 exactly
                float v = wqkv[idx];
                if (idx < 32768) v *= QSCALE;     // rows 0..127 = W_q
                wb[idx] = (bf16)v;
            }
        } else {
            wob[tid * 2]     = (bf16)wout[tid * 2];     // 32768 = 256*128
            wob[tid * 2 + 1] = (bf16)wout[tid * 2 + 1];
        }
        return;
    }
    const int b  = blockIdx.z;
    const int c0 = blockIdx.y * 64;
    const int i0 = blockIdx.x * 64;
    __shared__ float Ts[64][65];
    const float* xb = x + (size_t)b * CIN * NPOS;
    #pragma unroll
    for (int u = 0; u < 4; ++u) {
        int c = (t >> 4) + u * 16;
        int i = (t & 15) * 4;
        float4 v = *(const float4*)(xb + (size_t)(c0 + c) * NPOS + i0 + i);
        Ts[c][i] = v.x; Ts[c][i + 1] = v.y; Ts[c][i + 2] = v.z; Ts[c][i + 3] = v.w;
    }
    __syncthreads();
    int i  = t & 63;
    int cc = (t >> 6) * 16;
    B8 o0, o1;
    #pragma unroll
    for (int j = 0; j < 8; ++j) {
        o0.v[j] = (bf16)Ts[cc + j][i];
        o1.v[j] = (bf16)Ts[cc + 8 + j][i];
    }
    bf16* dst = xt + ((size_t)b * NPOS + i0 + i) * CIN + c0 + cc;
    *(bf16x8*)dst       = o0.v;
    *(bf16x8*)(dst + 8) = o1.v;
}

// ---------------- Kernel 1: qkv MFMA GEMM (R11 verbatim) ----------------
__global__ __launch_bounds__(256) void qkv_kernel(const bf16* __restrict__ xt,
                                                  const bf16* __restrict__ wb,
                                                  bf16* __restrict__ qb,
                                                  bf16* __restrict__ kb,
                                                  bf16* __restrict__ vtb) {
    const int i0 = blockIdx.x * 64;
    const int ot = blockIdx.y * 64;
    const int b  = blockIdx.z;
    const int t  = threadIdx.x;
    const int w  = t >> 6;
    const int lane = t & 63;
    const int quad = lane >> 4;
    const int li   = lane & 15;

    __shared__ bf16 Bs[64][36];   // [i_loc][k]

    f32x4 acc[4];
    #pragma unroll
    for (int n = 0; n < 4; ++n) acc[n] = (f32x4){0.f, 0.f, 0.f, 0.f};

    const bf16* xrow = xt + ((size_t)b * NPOS + i0) * CIN;
    const int si = t >> 2;            // 0..63
    const int sk = (t & 3) * 8;       // 0,8,16,24

    for (int k0 = 0; k0 < CIN; k0 += 32) {
        __syncthreads();
        B8 g0;
        g0.v = *(const bf16x8*)(xrow + (size_t)si * CIN + k0 + sk);
        *(bf16x4*)&Bs[si][sk]     = g0.h[0];
        *(bf16x4*)&Bs[si][sk + 4] = g0.h[1];
        __syncthreads();
        bf16x8 afrag = *(const bf16x8*)(wb + (size_t)(ot + w * 16 + li) * CIN + k0 + quad * 8);
        #pragma unroll
        for (int n = 0; n < 4; ++n) {
            B8 bf;
            bf.h[0] = *(const bf16x4*)&Bs[n * 16 + li][quad * 8];
            bf.h[1] = *(const bf16x4*)&Bs[n * 16 + li][quad * 8 + 4];
            acc[n] = __builtin_amdgcn_mfma_f32_16x16x32_bf16(afrag, bf.v, acc[n], 0, 0, 0);
        }
    }

    const int obase = ot + w * 16;
    const int sect  = obase >> 7;            // 0=q 1=k 2=v
    const int oo    = obase & 127;
    const int h     = oo >> 5;
    const int dbase = (oo & 31) + quad * 4;
    const int bh    = b * NHEAD + h;

    #pragma unroll
    for (int n = 0; n < 4; ++n) {
        int i = i0 + n * 16 + li;
        f32x4 v = acc[n];
        if (sect <= 1) {
            bf16x4 pk;
            #pragma unroll
            for (int r = 0; r < 4; ++r) pk[r] = (bf16)v[r];
            bf16* base = (sect == 0) ? qb : kb;
            *(bf16x4*)(base + ((size_t)bh * NPOS + i) * DHEAD + dbase) = pk;
        } else {
            #pragma unroll
            for (int r = 0; r < 4; ++r)
                vtb[((size_t)bh * DHEAD + dbase + r) * NPOS + i] = (bf16)v[r];
        }
    }
}

// ---------------- Kernel 2: MFMA flash attention, 16 rows/wave for 8 waves/SIMD ----------------
// R12: the register floor was the occupancy cap all session (32-row/wave state >64
// unified regs -> 4 waves/SIMD; R6 proved forcing 8 without shrinking state spills).
// Halve per-wave width: 16 i-rows/wave -> persistent {qf0,o00,o01,l0}=16 regs;
// exp moved BEFORE pv (P in 8 regs, stored after PV reads the old tile) so s dies
// before PV transients. Hand-counted peak live ~52-58 <= 64 -> (256,8) legitimate.
// Grid 2048 = 8 blocks/CU; plds 8.7 KB/block (69.6 KB/CU). NSPLIT=4, operand
// layouts identical to R11 minus the second row-group. prep/qkv/proj untouched.
__global__ __launch_bounds__(256, 8) void fattn_kernel(const bf16* __restrict__ qb,
                                                       const bf16* __restrict__ kb,
                                                       const bf16* __restrict__ vtb,
                                                       bf16* __restrict__ aop,
                                                       float* __restrict__ lpart) {
    const int id    = blockIdx.x;
    const int g     = id & 31;
    const int iblk  = id >> 5;           // 0..63
    const int bh    = g >> 2;
    const int split = g & 3;
    const int w     = threadIdx.x >> 6;
    const int lane  = threadIdx.x & 63;
    const int quad  = lane >> 4;
    const int li    = lane & 15;
    const int i0    = iblk * 64 + w * 16;
    const int j_lo  = split * 1024;

    const bf16* qrow = qb + (size_t)bh * NPOS * DHEAD;
    const bf16x8 qf0 = *(const bf16x8*)(qrow + (size_t)(i0 + li) * DHEAD + quad * 8);
    const bf16* kbase  = kb  + (size_t)bh * NPOS * DHEAD;
    const bf16* vtbase = vtb + (size_t)bh * DHEAD * NPOS;

    bf16x8 ones;
    #pragma unroll
    for (int j = 0; j < 8; ++j) ones[j] = (bf16)1.0f;

    f32x4 o00 = {0.f,0.f,0.f,0.f}, o01 = {0.f,0.f,0.f,0.f};
    f32x4 l0  = {0.f,0.f,0.f,0.f};
    __shared__ alignas(16) bf16 plds[4][16][68];   // [wave][i][j], 8,704 B, wave-private

    const f32x4 zero = {0.f,0.f,0.f,0.f};

    auto pv_step = [&](int jp) {
        #pragma unroll
        for (int h2 = 0; h2 < 2; ++h2) {
            B8 pf0;
            pf0.h[0] = *(const bf16x4*)&plds[w][li][h2 * 32 + quad * 8];
            pf0.h[1] = *(const bf16x4*)&plds[w][li][h2 * 32 + quad * 8 + 4];
            bf16x8 v0f = *(const bf16x8*)(vtbase + (size_t)li        * NPOS + jp + h2 * 32 + quad * 8);
            bf16x8 v1f = *(const bf16x8*)(vtbase + (size_t)(16 + li) * NPOS + jp + h2 * 32 + quad * 8);
            l0  = __builtin_amdgcn_mfma_f32_16x16x32_bf16(ones, pf0.v, l0,  0, 0, 0);
            o00 = __builtin_amdgcn_mfma_f32_16x16x32_bf16(v0f,  pf0.v, o00, 0, 0, 0);
            o01 = __builtin_amdgcn_mfma_f32_16x16x32_bf16(v1f,  pf0.v, o01, 0, 0, 0);
        }
    };

    #pragma unroll 1
    for (int it = 0; it < 16; ++it) {
        if ((it & 3) == 0) __builtin_amdgcn_s_barrier();   // loose lockstep for L1 stream sharing
        const int j0 = j_lo + it * 64;
        // K loads + QK MFMAs for tile it (4 MFMAs, 16 rows)
        bf16x8 kf[4];
        #pragma unroll
        for (int tt = 0; tt < 4; ++tt)
            kf[tt] = *(const bf16x8*)(kbase + (size_t)(j0 + 16 * tt + li) * DHEAD + quad * 8);
        f32x4 s0[4];
        #pragma unroll
        for (int tt = 0; tt < 4; ++tt)
            s0[tt] = __builtin_amdgcn_mfma_f32_16x16x32_bf16(kf[tt], qf0, zero, 0, 0, 0);
        // exp to registers (s dies here, before PV transients arrive)
        bf16x4 p0[4];
        #pragma unroll
        for (int tt = 0; tt < 4; ++tt) {
            #pragma unroll
            for (int r = 0; r < 4; ++r)
                p0[tt][r] = (bf16)__builtin_amdgcn_exp2f(s0[tt][r]);
        }
        // PV for tile it-1 (reads plds BEFORE this tile's store; wave-order DS => safe)
        if (it > 0) pv_step(j_lo + (it - 1) * 64);
        // store tile it into plds
        #pragma unroll
        for (int tt = 0; tt < 4; ++tt)
            *(bf16x4*)&plds[w][li][16 * tt + quad * 4] = p0[tt];
    }
    // drain: PV for the last tile
    pv_step(j_lo + 15 * 64);

    const int b = bh >> 2, h = bh & 3;
    {
        const int i = i0 + li;
        bf16* dst = aop + (((size_t)(split * NB + b) * NPOS + i) * HID) + h * DHEAD;
        bf16x4 pk0, pk1;
        #pragma unroll
        for (int r = 0; r < 4; ++r) { pk0[r] = (bf16)o00[r]; pk1[r] = (bf16)o01[r]; }
        *(bf16x4*)(dst + quad * 4)      = pk0;
        *(bf16x4*)(dst + 16 + quad * 4) = pk1;
        if (quad == 0) lpart[((size_t)split * NBH + bh) * NPOS + i] = l0[0];
    }
}

// ---------------- Kernel 3: proj GEMM with fused split-combine (R11 verbatim) ----------------
__global__ __launch_bounds__(256) void proj_kernel(const bf16* __restrict__ aop,
                                                   const float* __restrict__ lpart,
                                                   const bf16* __restrict__ wob,
                                                   const float* __restrict__ bout,
                                                   float* __restrict__ y) {
    const int i0 = blockIdx.x * 64;
    const int ot = blockIdx.y * 64;
    const int b  = blockIdx.z;
    const int t  = threadIdx.x;
    const int w  = t >> 6;
    const int lane = t & 63;
    const int quad = lane >> 4;
    const int li   = lane & 15;

    __shared__ bf16 Bs[64][132];   // [i_loc][c]

    // staging with combine: thread = (row, 32-channel chunk)
    {
        const int row = t >> 2;          // 0..63
        const int cp  = (t & 3) * 32;    // 0,32,64,96 (one head each)
        const int gi  = i0 + row;
        const int h   = cp >> 5;

        float lsum = 0.f;
        #pragma unroll
        for (int s = 0; s < NSPLIT; ++s)
            lsum += lpart[((size_t)s * NBH + b * NHEAD + h) * NPOS + gi];
        const float invl = __builtin_amdgcn_rcpf(lsum);

        float vals[32];
        #pragma unroll
        for (int j = 0; j < 32; ++j) vals[j] = 0.f;
        #pragma unroll
        for (int s = 0; s < NSPLIT; ++s) {
            const bf16* src = aop + (((size_t)(s * NB + b) * NPOS + gi) * HID) + cp;
            #pragma unroll
            for (int m = 0; m < 4; ++m) {
                bf16x8 u = *(const bf16x8*)(src + m * 8);
                #pragma unroll
                for (int j = 0; j < 8; ++j) vals[m * 8 + j] += (float)u[j];
            }
        }
        #pragma unroll
        for (int m = 0; m < 4; ++m) {
            B8 pk;
            #pragma unroll
            for (int j = 0; j < 8; ++j) pk.v[j] = (bf16)(vals[m * 8 + j] * invl);
            *(bf16x8*)&Bs[row][cp + m * 8] = pk.v;
        }
    }
    __syncthreads();

    f32x4 acc[4];
    #pragma unroll
    for (int n = 0; n < 4; ++n) acc[n] = (f32x4){0.f, 0.f, 0.f, 0.f};

    #pragma unroll
    for (int k0 = 0; k0 < HID; k0 += 32) {
        bf16x8 afrag = *(const bf16x8*)(wob + (size_t)(ot + w * 16 + li) * HID + k0 + quad * 8);
        #pragma unroll
        for (int n = 0; n < 4; ++n) {
            B8 bf;
            bf.h[0] = *(const bf16x4*)&Bs[n * 16 + li][k0 + quad * 8];
            bf.h[1] = *(const bf16x4*)&Bs[n * 16 + li][k0 + quad * 8 + 4];
            acc[n] = __builtin_amdgcn_mfma_f32_16x16x32_bf16(afrag, bf.v, acc[n], 0, 0, 0);
        }
    }

    float bias[4];
    #pragma unroll
    for (int r = 0; r < 4; ++r) bias[r] = bout[ot + w * 16 + quad * 4 + r];
    float* yb = y + (size_t)b * CIN * NPOS;
    #pragma unroll
    for (int n = 0; n < 4; ++n) {
        int i = i0 + n * 16 + li;
        #pragma unroll
        for (int r = 0; r < 4; ++r)
            yb[(size_t)(ot + w * 16 + quad * 4 + r) * NPOS + i] = acc[n][r] + bias[r];
    }
}

extern "C" void kernel_launch(void* const* d_in, const int* in_sizes, int n_in,
                              void* d_out, int out_size, void* d_ws, size_t ws_size,
                              hipStream_t stream) {
    const float* x    = (const float*)d_in[0];
    const float* wqkv = (const float*)d_in[1];
    const float* wout = (const float*)d_in[2];
    const float* bout = (const float*)d_in[3];
    float* y = (float*)d_out;
    char* ws = (char*)d_ws;

    bf16*  xt  = (bf16*)(ws + XT_OFF);
    bf16*  qb  = (bf16*)(ws + QB_OFF);
    bf16*  kb  = (bf16*)(ws + KB_OFF);
    bf16*  vtb = (bf16*)(ws + VT_OFF);
    bf16*  aop = (bf16*)(ws + AOP_OFF);
    float* lp  = (float*)(ws + LP_OFF);
    bf16*  wb  = (bf16*)(ws + WB_OFF);
    bf16*  wob = (bf16*)(ws + WOB_OFF);

    prep_kernel<<<dim3(64, 5, 2), 256, 0, stream>>>(x, wqkv, wout, xt, wb, wob);
    qkv_kernel<<<dim3(64, 6, 2), 256, 0, stream>>>(xt, wb, qb, kb, vtb);
    fattn_kernel<<<dim3(2048), 256, 0, stream>>>(qb, kb, vtb, aop, lp);
    proj_kernel<<<dim3(64, 4, 2), 256, 0, stream>>>(aop, lp, wob, bout, y);
}

// Round 8
// 130.266 us; speedup vs baseline: 1.3023x; 1.3023x over previous
//
#include <hip/hip_runtime.h>
#include <hip/hip_bf16.h>
#include <math.h>

#define NB 2
#define CIN 256
#define NPOS 4096          // 64*64
#define HID 128
#define NHEAD 4
#define DHEAD 32
#define NBH 8
#define NSPLIT 4
#define QSCALE 0.2550348676144781f   // 32^-0.5 * log2(e), folded into W_q

typedef __bf16 bf16;
typedef __attribute__((ext_vector_type(8))) __bf16 bf16x8;
typedef __attribute__((ext_vector_type(4))) __bf16 bf16x4;
typedef __attribute__((ext_vector_type(4))) float f32x4;

union B8 { bf16x8 v; bf16x4 h[2]; };

// ws layout (byte offsets), total 19,660,800 B (R0/R11 layout):
#define XT_OFF  0u            // xt  bf16 [2][4096][256]   4 MB
#define QB_OFF  4194304u      // qb  bf16 [8][4096][32]    2 MB  (W_q pre-scaled by QSCALE)
#define KB_OFF  6291456u      // kb  bf16 [8][4096][32]    2 MB
#define VT_OFF  8388608u      // vtb bf16 [8][32][4096]    2 MB  (V transposed)
#define AOP_OFF 10485760u     // aop bf16 [4][2][4096][128] 8 MB (partial O, [split][b][i][c])
#define LP_OFF  18874368u     // lp  f32  [4][8][4096]     512 KB
#define WB_OFF  19398656u     // wb  bf16 [384][256]       192 KB
#define WOB_OFF 19595264u     // wob bf16 [256][128]       64 KB

// ---------------- Kernel 0: prep — transpose x to bf16 [b][i][c]; cast weights (R11 verbatim) ----------------
__global__ __launch_bounds__(256) void prep_kernel(const float* __restrict__ x,
                                                   const float* __restrict__ wqkv,
                                                   const float* __restrict__ wout,
                                                   bf16* __restrict__ xt,
                                                   bf16* __restrict__ wb,
                                                   bf16* __restrict__ wob) {
    const int t = threadIdx.x;
    if (blockIdx.y == 4) {
        int tid = blockIdx.x * 256 + t;           // 0..16383
        if (blockIdx.z == 0) {
            #pragma unroll
            for (int u = 0; u < 6; ++u) {
                int idx = tid * 6 + u;            // 98304 = 384*256 exactly
                float v = wqkv[idx];
                if (idx < 32768) v *= QSCALE;     // rows 0..127 = W_q
                wb[idx] = (bf16)v;
            }
        } else {
            wob[tid * 2]     = (bf16)wout[tid * 2];     // 32768 = 256*128
            wob[tid * 2 + 1] = (bf16)wout[tid * 2 + 1];
        }
        return;
    }
    const int b  = blockIdx.z;
    const int c0 = blockIdx.y * 64;
    const int i0 = blockIdx.x * 64;
    __shared__ float Ts[64][65];
    const float* xb = x + (size_t)b * CIN * NPOS;
    #pragma unroll
    for (int u = 0; u < 4; ++u) {
        int c = (t >> 4) + u * 16;
        int i = (t & 15) * 4;
        float4 v = *(const float4*)(xb + (size_t)(c0 + c) * NPOS + i0 + i);
        Ts[c][i] = v.x; Ts[c][i + 1] = v.y; Ts[c][i + 2] = v.z; Ts[c][i + 3] = v.w;
    }
    __syncthreads();
    int i  = t & 63;
    int cc = (t >> 6) * 16;
    B8 o0, o1;
    #pragma unroll
    for (int j = 0; j < 8; ++j) {
        o0.v[j] = (bf16)Ts[cc + j][i];
        o1.v[j] = (bf16)Ts[cc + 8 + j][i];
    }
    bf16* dst = xt + ((size_t)b * NPOS + i0 + i) * CIN + c0 + cc;
    *(bf16x8*)dst       = o0.v;
    *(bf16x8*)(dst + 8) = o1.v;
}

// ---------------- Kernel 1: qkv MFMA GEMM — double-buffered LDS, 1 barrier/step ----------------
// R13: R11's qkv exposed the full global-load latency every k-step (2 barriers
// bracketing the stage). Now: Bs double-buffered (9.2 KB), next tile's load issued
// in regs BEFORE the MFMAs (drains under compute), store to the other buffer, ONE
// barrier per step. Hazards: step s reads buf[s&1] (written pre-barrier in s-1),
// writes buf[(s+1)&1] (last read pre-barrier in s-1) — one barrier between each
// conflicting pair. 8 barriers vs 16, load latency hidden.
__global__ __launch_bounds__(256) void qkv_kernel(const bf16* __restrict__ xt,
                                                  const bf16* __restrict__ wb,
                                                  bf16* __restrict__ qb,
                                                  bf16* __restrict__ kb,
                                                  bf16* __restrict__ vtb) {
    const int i0 = blockIdx.x * 64;
    const int ot = blockIdx.y * 64;
    const int b  = blockIdx.z;
    const int t  = threadIdx.x;
    const int w  = t >> 6;
    const int lane = t & 63;
    const int quad = lane >> 4;
    const int li   = lane & 15;

    __shared__ bf16 Bs[2][64][36];   // [buf][i_loc][k], 9,216 B

    f32x4 acc[4];
    #pragma unroll
    for (int n = 0; n < 4; ++n) acc[n] = (f32x4){0.f, 0.f, 0.f, 0.f};

    const bf16* xrow = xt + ((size_t)b * NPOS + i0) * CIN;
    const int si = t >> 2;            // 0..63
    const int sk = (t & 3) * 8;       // 0,8,16,24

    B8 g;
    g.v = *(const bf16x8*)(xrow + (size_t)si * CIN + sk);
    *(bf16x4*)&Bs[0][si][sk]     = g.h[0];
    *(bf16x4*)&Bs[0][si][sk + 4] = g.h[1];
    __syncthreads();

    #pragma unroll
    for (int s = 0; s < 8; ++s) {
        const int k0 = s * 32;
        if (s < 7)
            g.v = *(const bf16x8*)(xrow + (size_t)si * CIN + k0 + 32 + sk);   // next tile, drains under MFMA
        bf16x8 afrag = *(const bf16x8*)(wb + (size_t)(ot + w * 16 + li) * CIN + k0 + quad * 8);
        #pragma unroll
        for (int n = 0; n < 4; ++n) {
            B8 bf;
            bf.h[0] = *(const bf16x4*)&Bs[s & 1][n * 16 + li][quad * 8];
            bf.h[1] = *(const bf16x4*)&Bs[s & 1][n * 16 + li][quad * 8 + 4];
            acc[n] = __builtin_amdgcn_mfma_f32_16x16x32_bf16(afrag, bf.v, acc[n], 0, 0, 0);
        }
        if (s < 7) {
            *(bf16x4*)&Bs[(s + 1) & 1][si][sk]     = g.h[0];
            *(bf16x4*)&Bs[(s + 1) & 1][si][sk + 4] = g.h[1];
            __syncthreads();
        }
    }

    const int obase = ot + w * 16;
    const int sect  = obase >> 7;            // 0=q 1=k 2=v
    const int oo    = obase & 127;
    const int h     = oo >> 5;
    const int dbase = (oo & 31) + quad * 4;
    const int bh    = b * NHEAD + h;

    #pragma unroll
    for (int n = 0; n < 4; ++n) {
        int i = i0 + n * 16 + li;
        f32x4 v = acc[n];
        if (sect <= 1) {
            bf16x4 pk;
            #pragma unroll
            for (int r = 0; r < 4; ++r) pk[r] = (bf16)v[r];
            bf16* base = (sect == 0) ? qb : kb;
            *(bf16x4*)(base + ((size_t)bh * NPOS + i) * DHEAD + dbase) = pk;
        } else {
            #pragma unroll
            for (int r = 0; r < 4; ++r)
                vtb[((size_t)bh * DHEAD + dbase + r) * NPOS + i] = (bf16)v[r];
        }
    }
}

// ---------------- Kernel 2: MFMA flash attention (R11 verbatim — frozen) ----------------
// Boxed in from all directions: R6 fewer-regs=spill, R12 fewer-rows=L1-bound (2x
// slower at 85% occupancy), R8 reg-prefetch=pressure, R9 conflicts=0 & off-path.
// 32 rows/wave, 4 waves/SIMD, 51.4 us is this structure's operating point.
__global__ __launch_bounds__(256, 4) void fattn_kernel(const bf16* __restrict__ qb,
                                                       const bf16* __restrict__ kb,
                                                       const bf16* __restrict__ vtb,
                                                       bf16* __restrict__ aop,
                                                       float* __restrict__ lpart) {
    const int id    = blockIdx.x;
    const int g     = id & 31;
    const int iblk  = id >> 5;           // 0..31
    const int bh    = g >> 2;
    const int split = g & 3;
    const int w     = threadIdx.x >> 6;
    const int lane  = threadIdx.x & 63;
    const int quad  = lane >> 4;
    const int li    = lane & 15;
    const int i0    = iblk * 128 + w * 32;
    const int j_lo  = split * 1024;

    const bf16* qrow = qb + (size_t)bh * NPOS * DHEAD;
    const bf16x8 qf0 = *(const bf16x8*)(qrow + (size_t)(i0 + li) * DHEAD + quad * 8);
    const bf16x8 qf1 = *(const bf16x8*)(qrow + (size_t)(i0 + 16 + li) * DHEAD + quad * 8);
    const bf16* kbase  = kb  + (size_t)bh * NPOS * DHEAD;
    const bf16* vtbase = vtb + (size_t)bh * DHEAD * NPOS;

    bf16x8 ones;
    #pragma unroll
    for (int j = 0; j < 8; ++j) ones[j] = (bf16)1.0f;

    f32x4 o00 = {0.f,0.f,0.f,0.f}, o01 = {0.f,0.f,0.f,0.f};
    f32x4 o10 = {0.f,0.f,0.f,0.f}, o11 = {0.f,0.f,0.f,0.f};
    f32x4 l0  = {0.f,0.f,0.f,0.f}, l1  = {0.f,0.f,0.f,0.f};
    __shared__ alignas(16) bf16 plds[4][32][68];   // [wave][i][j], 17,408 B, wave-private

    const f32x4 zero = {0.f,0.f,0.f,0.f};

    auto pv_step = [&](int jp) {
        #pragma unroll
        for (int h2 = 0; h2 < 2; ++h2) {
            B8 pf0, pf1;
            pf0.h[0] = *(const bf16x4*)&plds[w][li][h2 * 32 + quad * 8];
            pf0.h[1] = *(const bf16x4*)&plds[w][li][h2 * 32 + quad * 8 + 4];
            pf1.h[0] = *(const bf16x4*)&plds[w][16 + li][h2 * 32 + quad * 8];
            pf1.h[1] = *(const bf16x4*)&plds[w][16 + li][h2 * 32 + quad * 8 + 4];
            bf16x8 v0f = *(const bf16x8*)(vtbase + (size_t)li        * NPOS + jp + h2 * 32 + quad * 8);
            bf16x8 v1f = *(const bf16x8*)(vtbase + (size_t)(16 + li) * NPOS + jp + h2 * 32 + quad * 8);
            l0  = __builtin_amdgcn_mfma_f32_16x16x32_bf16(ones, pf0.v, l0,  0, 0, 0);
            l1  = __builtin_amdgcn_mfma_f32_16x16x32_bf16(ones, pf1.v, l1,  0, 0, 0);
            o00 = __builtin_amdgcn_mfma_f32_16x16x32_bf16(v0f,  pf0.v, o00, 0, 0, 0);
            o01 = __builtin_amdgcn_mfma_f32_16x16x32_bf16(v1f,  pf0.v, o01, 0, 0, 0);
            o10 = __builtin_amdgcn_mfma_f32_16x16x32_bf16(v0f,  pf1.v, o10, 0, 0, 0);
            o11 = __builtin_amdgcn_mfma_f32_16x16x32_bf16(v1f,  pf1.v, o11, 0, 0, 0);
        }
    };

    for (int it = 0; it < 16; ++it) {
        if ((it & 3) == 0) __builtin_amdgcn_s_barrier();   // loose lockstep for L1 stream sharing
        const int j0 = j_lo + it * 64;
        // K loads + QK MFMAs for tile it
        bf16x8 kf[4];
        #pragma unroll
        for (int tt = 0; tt < 4; ++tt)
            kf[tt] = *(const bf16x8*)(kbase + (size_t)(j0 + 16 * tt + li) * DHEAD + quad * 8);
        f32x4 s0[4], s1[4];
        #pragma unroll
        for (int tt = 0; tt < 4; ++tt) {
            s0[tt] = __builtin_amdgcn_mfma_f32_16x16x32_bf16(kf[tt], qf0, zero, 0, 0, 0);
            s1[tt] = __builtin_amdgcn_mfma_f32_16x16x32_bf16(kf[tt], qf1, zero, 0, 0, 0);
        }
        // PV for tile it-1 (reads plds BEFORE this tile's writes; wave-order DS => safe)
        if (it > 0) pv_step(j_lo + (it - 1) * 64);
        // exp + pack + store tile it into plds
        #pragma unroll
        for (int tt = 0; tt < 4; ++tt) {
            bf16x4 p0, p1;
            #pragma unroll
            for (int r = 0; r < 4; ++r) {
                p0[r] = (bf16)__builtin_amdgcn_exp2f(s0[tt][r]);
                p1[r] = (bf16)__builtin_amdgcn_exp2f(s1[tt][r]);
            }
            *(bf16x4*)&plds[w][li][16 * tt + quad * 4]      = p0;
            *(bf16x4*)&plds[w][16 + li][16 * tt + quad * 4] = p1;
        }
    }
    // drain: PV for the last tile
    pv_step(j_lo + 15 * 64);

    const int b = bh >> 2, h = bh & 3;
    {
        const int i = i0 + li;
        bf16* dst = aop + (((size_t)(split * NB + b) * NPOS + i) * HID) + h * DHEAD;
        bf16x4 pk0, pk1;
        #pragma unroll
        for (int r = 0; r < 4; ++r) { pk0[r] = (bf16)o00[r]; pk1[r] = (bf16)o01[r]; }
        *(bf16x4*)(dst + quad * 4)      = pk0;
        *(bf16x4*)(dst + 16 + quad * 4) = pk1;
        if (quad == 0) lpart[((size_t)split * NBH + bh) * NPOS + i] = l0[0];
    }
    {
        const int i = i0 + 16 + li;
        bf16* dst = aop + (((size_t)(split * NB + b) * NPOS + i) * HID) + h * DHEAD;
        bf16x4 pk0, pk1;
        #pragma unroll
        for (int r = 0; r < 4; ++r) { pk0[r] = (bf16)o10[r]; pk1[r] = (bf16)o11[r]; }
        *(bf16x4*)(dst + quad * 4)      = pk0;
        *(bf16x4*)(dst + 16 + quad * 4) = pk1;
        if (quad == 0) lpart[((size_t)split * NBH + bh) * NPOS + i] = l1[0];
    }
}

// ---------------- Kernel 3: proj GEMM with fused split-combine (R11 verbatim) ----------------
__global__ __launch_bounds__(256) void proj_kernel(const bf16* __restrict__ aop,
                                                   const float* __restrict__ lpart,
                                                   const bf16* __restrict__ wob,
                                                   const float* __restrict__ bout,
                                                   float* __restrict__ y) {
    const int i0 = blockIdx.x * 64;
    const int ot = blockIdx.y * 64;
    const int b  = blockIdx.z;
    const int t  = threadIdx.x;
    const int w  = t >> 6;
    const int lane = t & 63;
    const int quad = lane >> 4;
    const int li   = lane & 15;

    __shared__ bf16 Bs[64][132];   // [i_loc][c]

    // staging with combine: thread = (row, 32-channel chunk)
    {
        const int row = t >> 2;          // 0..63
        const int cp  = (t & 3) * 32;    // 0,32,64,96 (one head each)
        const int gi  = i0 + row;
        const int h   = cp >> 5;

        float lsum = 0.f;
        #pragma unroll
        for (int s = 0; s < NSPLIT; ++s)
            lsum += lpart[((size_t)s * NBH + b * NHEAD + h) * NPOS + gi];
        const float invl = __builtin_amdgcn_rcpf(lsum);

        float vals[32];
        #pragma unroll
        for (int j = 0; j < 32; ++j) vals[j] = 0.f;
        #pragma unroll
        for (int s = 0; s < NSPLIT; ++s) {
            const bf16* src = aop + (((size_t)(s * NB + b) * NPOS + gi) * HID) + cp;
            #pragma unroll
            for (int m = 0; m < 4; ++m) {
                bf16x8 u = *(const bf16x8*)(src + m * 8);
                #pragma unroll
                for (int j = 0; j < 8; ++j) vals[m * 8 + j] += (float)u[j];
            }
        }
        #pragma unroll
        for (int m = 0; m < 4; ++m) {
            B8 pk;
            #pragma unroll
            for (int j = 0; j < 8; ++j) pk.v[j] = (bf16)(vals[m * 8 + j] * invl);
            *(bf16x8*)&Bs[row][cp + m * 8] = pk.v;
        }
    }
    __syncthreads();

    f32x4 acc[4];
    #pragma unroll
    for (int n = 0; n < 4; ++n) acc[n] = (f32x4){0.f, 0.f, 0.f, 0.f};

    #pragma unroll
    for (int k0 = 0; k0 < HID; k0 += 32) {
        bf16x8 afrag = *(const bf16x8*)(wob + (size_t)(ot + w * 16 + li) * HID + k0 + quad * 8);
        #pragma unroll
        for (int n = 0; n < 4; ++n) {
            B8 bf;
            bf.h[0] = *(const bf16x4*)&Bs[n * 16 + li][k0 + quad * 8];
            bf.h[1] = *(const bf16x4*)&Bs[n * 16 + li][k0 + quad * 8 + 4];
            acc[n] = __builtin_amdgcn_mfma_f32_16x16x32_bf16(afrag, bf.v, acc[n], 0, 0, 0);
        }
    }

    float bias[4];
    #pragma unroll
    for (int r = 0; r < 4; ++r) bias[r] = bout[ot + w * 16 + quad * 4 + r];
    float* yb = y + (size_t)b * CIN * NPOS;
    #pragma unroll
    for (int n = 0; n < 4; ++n) {
        int i = i0 + n * 16 + li;
        #pragma unroll
        for (int r = 0; r < 4; ++r)
            yb[(size_t)(ot + w * 16 + quad * 4 + r) * NPOS + i] = acc[n][r] + bias[r];
    }
}

extern "C" void kernel_launch(void* const* d_in, const int* in_sizes, int n_in,
                              void* d_out, int out_size, void* d_ws, size_t ws_size,
                              hipStream_t stream) {
    const float* x    = (const float*)d_in[0];
    const float* wqkv = (const float*)d_in[1];
    const float* wout = (const float*)d_in[2];
    const float* bout = (const float*)d_in[3];
    float* y = (float*)d_out;
    char* ws = (char*)d_ws;

    bf16*  xt  = (bf16*)(ws + XT_OFF);
    bf16*  qb  = (bf16*)(ws + QB_OFF);
    bf16*  kb  = (bf16*)(ws + KB_OFF);
    bf16*  vtb = (bf16*)(ws + VT_OFF);
    bf16*  aop = (bf16*)(ws + AOP_OFF);
    float* lp  = (float*)(ws + LP_OFF);
    bf16*  wb  = (bf16*)(ws + WB_OFF);
    bf16*  wob = (bf16*)(ws + WOB_OFF);

    prep_kernel<<<dim3(64, 5, 2), 256, 0, stream>>>(x, wqkv, wout, xt, wb, wob);
    qkv_kernel<<<dim3(64, 6, 2), 256, 0, stream>>>(xt, wb, qb, kb, vtb);
    fattn_kernel<<<dim3(1024), 256, 0, stream>>>(qb, kb, vtb, aop, lp);
    proj_kernel<<<dim3(64, 4, 2), 256, 0, stream>>>(aop, lp, wob, bout, y);
}

// Round 9
// 110.718 us; speedup vs baseline: 1.5323x; 1.1766x over previous
//
#include <hip/hip_runtime.h>
#include <hip/hip_bf16.h>
#include <math.h>

#define NB 2
#define CIN 256
#define NPOS 4096          // 64*64
#define HID 128
#define NHEAD 4
#define DHEAD 32
#define NBH 8
#define NSPLIT 4
#define QSCALE 0.2550348676144781f   // 32^-0.5 * log2(e), folded into W_q

typedef __bf16 bf16;
typedef __attribute__((ext_vector_type(8))) __bf16 bf16x8;
typedef __attribute__((ext_vector_type(4))) __bf16 bf16x4;
typedef __attribute__((ext_vector_type(4))) float f32x4;

union B8 { bf16x8 v; bf16x4 h[2]; };

// ws layout (byte offsets), total 19,660,800 B (R0/R11 layout):
#define XT_OFF  0u            // xt  bf16 [2][4096][256]   4 MB
#define QB_OFF  4194304u      // qb  bf16 [8][4096][32]    2 MB  (W_q pre-scaled by QSCALE)
#define KB_OFF  6291456u      // kb  bf16 [8][4096][32]    2 MB
#define VT_OFF  8388608u      // vtb bf16 [8][32][4096]    2 MB  (V transposed)
#define AOP_OFF 10485760u     // aop bf16 [4][2][4096][128] 8 MB (partial O, [split][b][i][c])
#define LP_OFF  18874368u     // lp  f32  [4][8][4096]     512 KB
#define WB_OFF  19398656u     // wb  bf16 [384][256]       192 KB
#define WOB_OFF 19595264u     // wob bf16 [256][128]       64 KB

// ---------------- Kernel 0: prep — transpose x to bf16 [b][i][c]; cast weights (R11 verbatim) ----------------
__global__ __launch_bounds__(256) void prep_kernel(const float* __restrict__ x,
                                                   const float* __restrict__ wqkv,
                                                   const float* __restrict__ wout,
                                                   bf16* __restrict__ xt,
                                                   bf16* __restrict__ wb,
                                                   bf16* __restrict__ wob) {
    const int t = threadIdx.x;
    if (blockIdx.y == 4) {
        int tid = blockIdx.x * 256 + t;           // 0..16383
        if (blockIdx.z == 0) {
            #pragma unroll
            for (int u = 0; u < 6; ++u) {
                int idx = tid * 6 + u;            // 98304 = 384*256 exactly
                float v = wqkv[idx];
                if (idx < 32768) v *= QSCALE;     // rows 0..127 = W_q
                wb[idx] = (bf16)v;
            }
        } else {
            wob[tid * 2]     = (bf16)wout[tid * 2];     // 32768 = 256*128
            wob[tid * 2 + 1] = (bf16)wout[tid * 2 + 1];
        }
        return;
    }
    const int b  = blockIdx.z;
    const int c0 = blockIdx.y * 64;
    const int i0 = blockIdx.x * 64;
    __shared__ float Ts[64][65];
    const float* xb = x + (size_t)b * CIN * NPOS;
    #pragma unroll
    for (int u = 0; u < 4; ++u) {
        int c = (t >> 4) + u * 16;
        int i = (t & 15) * 4;
        float4 v = *(const float4*)(xb + (size_t)(c0 + c) * NPOS + i0 + i);
        Ts[c][i] = v.x; Ts[c][i + 1] = v.y; Ts[c][i + 2] = v.z; Ts[c][i + 3] = v.w;
    }
    __syncthreads();
    int i  = t & 63;
    int cc = (t >> 6) * 16;
    B8 o0, o1;
    #pragma unroll
    for (int j = 0; j < 8; ++j) {
        o0.v[j] = (bf16)Ts[cc + j][i];
        o1.v[j] = (bf16)Ts[cc + 8 + j][i];
    }
    bf16* dst = xt + ((size_t)b * NPOS + i0 + i) * CIN + c0 + cc;
    *(bf16x8*)dst       = o0.v;
    *(bf16x8*)(dst + 8) = o1.v;
}

// ---------------- Kernel 1: qkv MFMA GEMM (R11 verbatim) ----------------
__global__ __launch_bounds__(256) void qkv_kernel(const bf16* __restrict__ xt,
                                                  const bf16* __restrict__ wb,
                                                  bf16* __restrict__ qb,
                                                  bf16* __restrict__ kb,
                                                  bf16* __restrict__ vtb) {
    const int i0 = blockIdx.x * 64;
    const int ot = blockIdx.y * 64;
    const int b  = blockIdx.z;
    const int t  = threadIdx.x;
    const int w  = t >> 6;
    const int lane = t & 63;
    const int quad = lane >> 4;
    const int li   = lane & 15;

    __shared__ bf16 Bs[64][36];   // [i_loc][k]

    f32x4 acc[4];
    #pragma unroll
    for (int n = 0; n < 4; ++n) acc[n] = (f32x4){0.f, 0.f, 0.f, 0.f};

    const bf16* xrow = xt + ((size_t)b * NPOS + i0) * CIN;
    const int si = t >> 2;            // 0..63
    const int sk = (t & 3) * 8;       // 0,8,16,24

    for (int k0 = 0; k0 < CIN; k0 += 32) {
        __syncthreads();
        B8 g0;
        g0.v = *(const bf16x8*)(xrow + (size_t)si * CIN + k0 + sk);
        *(bf16x4*)&Bs[si][sk]     = g0.h[0];
        *(bf16x4*)&Bs[si][sk + 4] = g0.h[1];
        __syncthreads();
        bf16x8 afrag = *(const bf16x8*)(wb + (size_t)(ot + w * 16 + li) * CIN + k0 + quad * 8);
        #pragma unroll
        for (int n = 0; n < 4; ++n) {
            B8 bf;
            bf.h[0] = *(const bf16x4*)&Bs[n * 16 + li][quad * 8];
            bf.h[1] = *(const bf16x4*)&Bs[n * 16 + li][quad * 8 + 4];
            acc[n] = __builtin_amdgcn_mfma_f32_16x16x32_bf16(afrag, bf.v, acc[n], 0, 0, 0);
        }
    }

    const int obase = ot + w * 16;
    const int sect  = obase >> 7;            // 0=q 1=k 2=v
    const int oo    = obase & 127;
    const int h     = oo >> 5;
    const int dbase = (oo & 31) + quad * 4;
    const int bh    = b * NHEAD + h;

    #pragma unroll
    for (int n = 0; n < 4; ++n) {
        int i = i0 + n * 16 + li;
        f32x4 v = acc[n];
        if (sect <= 1) {
            bf16x4 pk;
            #pragma unroll
            for (int r = 0; r < 4; ++r) pk[r] = (bf16)v[r];
            bf16* base = (sect == 0) ? qb : kb;
            *(bf16x4*)(base + ((size_t)bh * NPOS + i) * DHEAD + dbase) = pk;
        } else {
            #pragma unroll
            for (int r = 0; r < 4; ++r)
                vtb[((size_t)bh * DHEAD + dbase + r) * NPOS + i] = (bf16)v[r];
        }
    }
}

// ---------------- Kernel 2: MFMA flash attention — cooperative LDS K/V staging ----------------
// R14: the measured stall (MfmaUtil 15, VALU 21, 60% idle) is L1/VMEM return BW:
// all 4 waves load the SAME K/V tiles (128 KB/CU/iter demand, 32 KB unique).
// Fix: double-buffered cooperative staging — each wave stages 1KB K + 1KB V
// (2 global b128/wave/iter, 4x VMEM dedup); fragments come from LDS (~120cy).
// PV is same-iteration (single-barrier double-buffer correctness: all reads of
// buf[cur] in iter it; write buf[cur^1] separated from its readers by one barrier).
// V-tile slot-XOR swizzle (slot ^= row&7, at ds_write AND ds_read) reaches the
// 8-cy b128 floor. plds/P path, NSPLIT=4, epilogue unchanged from R11.
__global__ __launch_bounds__(256, 4) void fattn_kernel(const bf16* __restrict__ qb,
                                                       const bf16* __restrict__ kb,
                                                       const bf16* __restrict__ vtb,
                                                       bf16* __restrict__ aop,
                                                       float* __restrict__ lpart) {
    const int id    = blockIdx.x;
    const int g     = id & 31;
    const int iblk  = id >> 5;           // 0..31
    const int bh    = g >> 2;
    const int split = g & 3;
    const int w     = threadIdx.x >> 6;
    const int lane  = threadIdx.x & 63;
    const int quad  = lane >> 4;
    const int li    = lane & 15;
    const int i0    = iblk * 128 + w * 32;
    const int j_lo  = split * 1024;

    const bf16* qrow = qb + (size_t)bh * NPOS * DHEAD;
    const bf16x8 qf0 = *(const bf16x8*)(qrow + (size_t)(i0 + li) * DHEAD + quad * 8);
    const bf16x8 qf1 = *(const bf16x8*)(qrow + (size_t)(i0 + 16 + li) * DHEAD + quad * 8);
    const bf16* kbase  = kb  + (size_t)bh * NPOS * DHEAD;
    const bf16* vtbase = vtb + (size_t)bh * DHEAD * NPOS;

    bf16x8 ones;
    #pragma unroll
    for (int j = 0; j < 8; ++j) ones[j] = (bf16)1.0f;

    f32x4 o00 = {0.f,0.f,0.f,0.f}, o01 = {0.f,0.f,0.f,0.f};
    f32x4 o10 = {0.f,0.f,0.f,0.f}, o11 = {0.f,0.f,0.f,0.f};
    f32x4 l0  = {0.f,0.f,0.f,0.f}, l1  = {0.f,0.f,0.f,0.f};

    __shared__ alignas(16) bf16 Kbuf[2][64][32];   // [buf][j_loc][d], 8 KB
    __shared__ alignas(16) bf16 Vbuf[2][32][64];   // [buf][d][j_loc], 8 KB (slot-swizzled)
    __shared__ alignas(16) bf16 plds[4][32][68];   // [wave][i][j], 17,408 B, wave-private

    const f32x4 zero = {0.f,0.f,0.f,0.f};

    // staging geometry: each wave stages 16 K-rows (1 KB) + 8 V-rows (1 KB)
    const int krow = w * 16 + (lane >> 2);        // 0..63 (j within tile)
    const int kcol = (lane & 3) * 8;              // d chunk (16 B)
    const int vrow = w * 8 + (lane >> 3);         // 0..31 (d)
    const int vchk = lane & 7;                    // j chunk (16 B)
    const int vslot = vchk ^ (vrow & 7);          // swizzled LDS slot
    const bf16* ksrc = kbase + (size_t)krow * DHEAD + kcol;
    const bf16* vsrc = vtbase + (size_t)vrow * NPOS + vchk * 8;

    bf16x8 kg, vg;

    // prologue: stage tile 0 into buf 0
    kg = *(const bf16x8*)(ksrc + (size_t)j_lo * DHEAD);
    vg = *(const bf16x8*)(vsrc + j_lo);
    *(bf16x8*)&Kbuf[0][krow][kcol]      = kg;
    *(bf16x8*)&Vbuf[0][vrow][vslot * 8] = vg;
    __syncthreads();

    for (int it = 0; it < 16; ++it) {
        const int cur = it & 1;
        const int j0  = j_lo + it * 64;
        // issue next tile's global loads (drain under this iteration's compute)
        if (it < 15) {
            kg = *(const bf16x8*)(ksrc + (size_t)(j0 + 64) * DHEAD);
            vg = *(const bf16x8*)(vsrc + j0 + 64);
        }
        // QK from Kbuf[cur]
        bf16x8 kf[4];
        #pragma unroll
        for (int tt = 0; tt < 4; ++tt)
            kf[tt] = *(const bf16x8*)&Kbuf[cur][16 * tt + li][quad * 8];
        f32x4 s0[4], s1[4];
        #pragma unroll
        for (int tt = 0; tt < 4; ++tt) {
            s0[tt] = __builtin_amdgcn_mfma_f32_16x16x32_bf16(kf[tt], qf0, zero, 0, 0, 0);
            s1[tt] = __builtin_amdgcn_mfma_f32_16x16x32_bf16(kf[tt], qf1, zero, 0, 0, 0);
        }
        // exp + pack + store into plds (wave-private; same-wave read below is ordered)
        #pragma unroll
        for (int tt = 0; tt < 4; ++tt) {
            bf16x4 p0, p1;
            #pragma unroll
            for (int r = 0; r < 4; ++r) {
                p0[r] = (bf16)__builtin_amdgcn_exp2f(s0[tt][r]);
                p1[r] = (bf16)__builtin_amdgcn_exp2f(s1[tt][r]);
            }
            *(bf16x4*)&plds[w][li][16 * tt + quad * 4]      = p0;
            *(bf16x4*)&plds[w][16 + li][16 * tt + quad * 4] = p1;
        }
        // PV (same tile) from plds + Vbuf[cur]
        #pragma unroll
        for (int h2 = 0; h2 < 2; ++h2) {
            B8 pf0, pf1;
            pf0.h[0] = *(const bf16x4*)&plds[w][li][h2 * 32 + quad * 8];
            pf0.h[1] = *(const bf16x4*)&plds[w][li][h2 * 32 + quad * 8 + 4];
            pf1.h[0] = *(const bf16x4*)&plds[w][16 + li][h2 * 32 + quad * 8];
            pf1.h[1] = *(const bf16x4*)&plds[w][16 + li][h2 * 32 + quad * 8 + 4];
            const int s0s = (h2 * 4 + quad) ^ (li & 7);   // read swizzle matches write
            bf16x8 v0f = *(const bf16x8*)&Vbuf[cur][li][s0s * 8];
            bf16x8 v1f = *(const bf16x8*)&Vbuf[cur][16 + li][s0s * 8];
            l0  = __builtin_amdgcn_mfma_f32_16x16x32_bf16(ones, pf0.v, l0,  0, 0, 0);
            l1  = __builtin_amdgcn_mfma_f32_16x16x32_bf16(ones, pf1.v, l1,  0, 0, 0);
            o00 = __builtin_amdgcn_mfma_f32_16x16x32_bf16(v0f,  pf0.v, o00, 0, 0, 0);
            o01 = __builtin_amdgcn_mfma_f32_16x16x32_bf16(v1f,  pf0.v, o01, 0, 0, 0);
            o10 = __builtin_amdgcn_mfma_f32_16x16x32_bf16(v0f,  pf1.v, o10, 0, 0, 0);
            o11 = __builtin_amdgcn_mfma_f32_16x16x32_bf16(v1f,  pf1.v, o11, 0, 0, 0);
        }
        // stage next tile into the other buffer (its readers are past the barrier)
        if (it < 15) {
            *(bf16x8*)&Kbuf[cur ^ 1][krow][kcol]      = kg;
            *(bf16x8*)&Vbuf[cur ^ 1][vrow][vslot * 8] = vg;
        }
        __syncthreads();
    }

    const int b = bh >> 2, h = bh & 3;
    {
        const int i = i0 + li;
        bf16* dst = aop + (((size_t)(split * NB + b) * NPOS + i) * HID) + h * DHEAD;
        bf16x4 pk0, pk1;
        #pragma unroll
        for (int r = 0; r < 4; ++r) { pk0[r] = (bf16)o00[r]; pk1[r] = (bf16)o01[r]; }
        *(bf16x4*)(dst + quad * 4)      = pk0;
        *(bf16x4*)(dst + 16 + quad * 4) = pk1;
        if (quad == 0) lpart[((size_t)split * NBH + bh) * NPOS + i] = l0[0];
    }
    {
        const int i = i0 + 16 + li;
        bf16* dst = aop + (((size_t)(split * NB + b) * NPOS + i) * HID) + h * DHEAD;
        bf16x4 pk0, pk1;
        #pragma unroll
        for (int r = 0; r < 4; ++r) { pk0[r] = (bf16)o10[r]; pk1[r] = (bf16)o11[r]; }
        *(bf16x4*)(dst + quad * 4)      = pk0;
        *(bf16x4*)(dst + 16 + quad * 4) = pk1;
        if (quad == 0) lpart[((size_t)split * NBH + bh) * NPOS + i] = l1[0];
    }
}

// ---------------- Kernel 3: proj GEMM with fused split-combine (R11 verbatim) ----------------
__global__ __launch_bounds__(256) void proj_kernel(const bf16* __restrict__ aop,
                                                   const float* __restrict__ lpart,
                                                   const bf16* __restrict__ wob,
                                                   const float* __restrict__ bout,
                                                   float* __restrict__ y) {
    const int i0 = blockIdx.x * 64;
    const int ot = blockIdx.y * 64;
    const int b  = blockIdx.z;
    const int t  = threadIdx.x;
    const int w  = t >> 6;
    const int lane = t & 63;
    const int quad = lane >> 4;
    const int li   = lane & 15;

    __shared__ bf16 Bs[64][132];   // [i_loc][c]

    // staging with combine: thread = (row, 32-channel chunk)
    {
        const int row = t >> 2;          // 0..63
        const int cp  = (t & 3) * 32;    // 0,32,64,96 (one head each)
        const int gi  = i0 + row;
        const int h   = cp >> 5;

        float lsum = 0.f;
        #pragma unroll
        for (int s = 0; s < NSPLIT; ++s)
            lsum += lpart[((size_t)s * NBH + b * NHEAD + h) * NPOS + gi];
        const float invl = __builtin_amdgcn_rcpf(lsum);

        float vals[32];
        #pragma unroll
        for (int j = 0; j < 32; ++j) vals[j] = 0.f;
        #pragma unroll
        for (int s = 0; s < NSPLIT; ++s) {
            const bf16* src = aop + (((size_t)(s * NB + b) * NPOS + gi) * HID) + cp;
            #pragma unroll
            for (int m = 0; m < 4; ++m) {
                bf16x8 u = *(const bf16x8*)(src + m * 8);
                #pragma unroll
                for (int j = 0; j < 8; ++j) vals[m * 8 + j] += (float)u[j];
            }
        }
        #pragma unroll
        for (int m = 0; m < 4; ++m) {
            B8 pk;
            #pragma unroll
            for (int j = 0; j < 8; ++j) pk.v[j] = (bf16)(vals[m * 8 + j] * invl);
            *(bf16x8*)&Bs[row][cp + m * 8] = pk.v;
        }
    }
    __syncthreads();

    f32x4 acc[4];
    #pragma unroll
    for (int n = 0; n < 4; ++n) acc[n] = (f32x4){0.f, 0.f, 0.f, 0.f};

    #pragma unroll
    for (int k0 = 0; k0 < HID; k0 += 32) {
        bf16x8 afrag = *(const bf16x8*)(wob + (size_t)(ot + w * 16 + li) * HID + k0 + quad * 8);
        #pragma unroll
        for (int n = 0; n < 4; ++n) {
            B8 bf;
            bf.h[0] = *(const bf16x4*)&Bs[n * 16 + li][k0 + quad * 8];
            bf.h[1] = *(const bf16x4*)&Bs[n * 16 + li][k0 + quad * 8 + 4];
            acc[n] = __builtin_amdgcn_mfma_f32_16x16x32_bf16(afrag, bf.v, acc[n], 0, 0, 0);
        }
    }

    float bias[4];
    #pragma unroll
    for (int r = 0; r < 4; ++r) bias[r] = bout[ot + w * 16 + quad * 4 + r];
    float* yb = y + (size_t)b * CIN * NPOS;
    #pragma unroll
    for (int n = 0; n < 4; ++n) {
        int i = i0 + n * 16 + li;
        #pragma unroll
        for (int r = 0; r < 4; ++r)
            yb[(size_t)(ot + w * 16 + quad * 4 + r) * NPOS + i] = acc[n][r] + bias[r];
    }
}

extern "C" void kernel_launch(void* const* d_in, const int* in_sizes, int n_in,
                              void* d_out, int out_size, void* d_ws, size_t ws_size,
                              hipStream_t stream) {
    const float* x    = (const float*)d_in[0];
    const float* wqkv = (const float*)d_in[1];
    const float* wout = (const float*)d_in[2];
    const float* bout = (const float*)d_in[3];
    float* y = (float*)d_out;
    char* ws = (char*)d_ws;

    bf16*  xt  = (bf16*)(ws + XT_OFF);
    bf16*  qb  = (bf16*)(ws + QB_OFF);
    bf16*  kb  = (bf16*)(ws + KB_OFF);
    bf16*  vtb = (bf16*)(ws + VT_OFF);
    bf16*  aop = (bf16*)(ws + AOP_OFF);
    float* lp  = (float*)(ws + LP_OFF);
    bf16*  wb  = (bf16*)(ws + WB_OFF);
    bf16*  wob = (bf16*)(ws + WOB_OFF);

    prep_kernel<<<dim3(64, 5, 2), 256, 0, stream>>>(x, wqkv, wout, xt, wb, wob);
    qkv_kernel<<<dim3(64, 6, 2), 256, 0, stream>>>(xt, wb, qb, kb, vtb);
    fattn_kernel<<<dim3(1024), 256, 0, stream>>>(qb, kb, vtb, aop, lp);
    proj_kernel<<<dim3(64, 4, 2), 256, 0, stream>>>(aop, lp, wob, bout, y);
}

// Round 10
// 107.885 us; speedup vs baseline: 1.5725x; 1.0263x over previous
//
#include <hip/hip_runtime.h>
#include <hip/hip_bf16.h>
#include <math.h>

#define NB 2
#define CIN 256
#define NPOS 4096          // 64*64
#define HID 128
#define NHEAD 4
#define DHEAD 32
#define NBH 8
#define NSPLIT 4
#define QSCALE 0.2550348676144781f   // 32^-0.5 * log2(e), folded into W_q

typedef __bf16 bf16;
typedef __attribute__((ext_vector_type(8))) __bf16 bf16x8;
typedef __attribute__((ext_vector_type(4))) __bf16 bf16x4;
typedef __attribute__((ext_vector_type(4))) float f32x4;

union B8 { bf16x8 v; bf16x4 h[2]; };

// ws layout (byte offsets), total 19,660,800 B (R0/R11 layout):
#define XT_OFF  0u            // xt  bf16 [2][4096][256]   4 MB
#define QB_OFF  4194304u      // qb  bf16 [8][4096][32]    2 MB  (W_q pre-scaled by QSCALE)
#define KB_OFF  6291456u      // kb  bf16 [8][4096][32]    2 MB
#define VT_OFF  8388608u      // vtb bf16 [8][32][4096]    2 MB  (V transposed)
#define AOP_OFF 10485760u     // aop bf16 [4][2][4096][128] 8 MB (partial O, [split][b][i][c])
#define LP_OFF  18874368u     // lp  f32  [4][8][4096]     512 KB
#define WB_OFF  19398656u     // wb  bf16 [384][256]       192 KB
#define WOB_OFF 19595264u     // wob bf16 [256][128]       64 KB

// ---------------- Kernel 0: prep — transpose x to bf16 [b][i][c]; cast weights (R14 verbatim) ----------------
__global__ __launch_bounds__(256) void prep_kernel(const float* __restrict__ x,
                                                   const float* __restrict__ wqkv,
                                                   const float* __restrict__ wout,
                                                   bf16* __restrict__ xt,
                                                   bf16* __restrict__ wb,
                                                   bf16* __restrict__ wob) {
    const int t = threadIdx.x;
    if (blockIdx.y == 4) {
        int tid = blockIdx.x * 256 + t;           // 0..16383
        if (blockIdx.z == 0) {
            #pragma unroll
            for (int u = 0; u < 6; ++u) {
                int idx = tid * 6 + u;            // 98304 = 384*256 exactly
                float v = wqkv[idx];
                if (idx < 32768) v *= QSCALE;     // rows 0..127 = W_q
                wb[idx] = (bf16)v;
            }
        } else {
            wob[tid * 2]     = (bf16)wout[tid * 2];     // 32768 = 256*128
            wob[tid * 2 + 1] = (bf16)wout[tid * 2 + 1];
        }
        return;
    }
    const int b  = blockIdx.z;
    const int c0 = blockIdx.y * 64;
    const int i0 = blockIdx.x * 64;
    __shared__ float Ts[64][65];
    const float* xb = x + (size_t)b * CIN * NPOS;
    #pragma unroll
    for (int u = 0; u < 4; ++u) {
        int c = (t >> 4) + u * 16;
        int i = (t & 15) * 4;
        float4 v = *(const float4*)(xb + (size_t)(c0 + c) * NPOS + i0 + i);
        Ts[c][i] = v.x; Ts[c][i + 1] = v.y; Ts[c][i + 2] = v.z; Ts[c][i + 3] = v.w;
    }
    __syncthreads();
    int i  = t & 63;
    int cc = (t >> 6) * 16;
    B8 o0, o1;
    #pragma unroll
    for (int j = 0; j < 8; ++j) {
        o0.v[j] = (bf16)Ts[cc + j][i];
        o1.v[j] = (bf16)Ts[cc + 8 + j][i];
    }
    bf16* dst = xt + ((size_t)b * NPOS + i0 + i) * CIN + c0 + cc;
    *(bf16x8*)dst       = o0.v;
    *(bf16x8*)(dst + 8) = o1.v;
}

// ---------------- Kernel 1: qkv MFMA GEMM (R14 verbatim) ----------------
__global__ __launch_bounds__(256) void qkv_kernel(const bf16* __restrict__ xt,
                                                  const bf16* __restrict__ wb,
                                                  bf16* __restrict__ qb,
                                                  bf16* __restrict__ kb,
                                                  bf16* __restrict__ vtb) {
    const int i0 = blockIdx.x * 64;
    const int ot = blockIdx.y * 64;
    const int b  = blockIdx.z;
    const int t  = threadIdx.x;
    const int w  = t >> 6;
    const int lane = t & 63;
    const int quad = lane >> 4;
    const int li   = lane & 15;

    __shared__ bf16 Bs[64][36];   // [i_loc][k]

    f32x4 acc[4];
    #pragma unroll
    for (int n = 0; n < 4; ++n) acc[n] = (f32x4){0.f, 0.f, 0.f, 0.f};

    const bf16* xrow = xt + ((size_t)b * NPOS + i0) * CIN;
    const int si = t >> 2;            // 0..63
    const int sk = (t & 3) * 8;       // 0,8,16,24

    for (int k0 = 0; k0 < CIN; k0 += 32) {
        __syncthreads();
        B8 g0;
        g0.v = *(const bf16x8*)(xrow + (size_t)si * CIN + k0 + sk);
        *(bf16x4*)&Bs[si][sk]     = g0.h[0];
        *(bf16x4*)&Bs[si][sk + 4] = g0.h[1];
        __syncthreads();
        bf16x8 afrag = *(const bf16x8*)(wb + (size_t)(ot + w * 16 + li) * CIN + k0 + quad * 8);
        #pragma unroll
        for (int n = 0; n < 4; ++n) {
            B8 bf;
            bf.h[0] = *(const bf16x4*)&Bs[n * 16 + li][quad * 8];
            bf.h[1] = *(const bf16x4*)&Bs[n * 16 + li][quad * 8 + 4];
            acc[n] = __builtin_amdgcn_mfma_f32_16x16x32_bf16(afrag, bf.v, acc[n], 0, 0, 0);
        }
    }

    const int obase = ot + w * 16;
    const int sect  = obase >> 7;            // 0=q 1=k 2=v
    const int oo    = obase & 127;
    const int h     = oo >> 5;
    const int dbase = (oo & 31) + quad * 4;
    const int bh    = b * NHEAD + h;

    #pragma unroll
    for (int n = 0; n < 4; ++n) {
        int i = i0 + n * 16 + li;
        f32x4 v = acc[n];
        if (sect <= 1) {
            bf16x4 pk;
            #pragma unroll
            for (int r = 0; r < 4; ++r) pk[r] = (bf16)v[r];
            bf16* base = (sect == 0) ? qb : kb;
            *(bf16x4*)(base + ((size_t)bh * NPOS + i) * DHEAD + dbase) = pk;
        } else {
            #pragma unroll
            for (int r = 0; r < 4; ++r)
                vtb[((size_t)bh * DHEAD + dbase + r) * NPOS + i] = (bf16)v[r];
        }
    }
}

// ---------------- Kernel 2: MFMA flash attention — cooperative LDS K/V staging (R14 verbatim) ----------------
__global__ __launch_bounds__(256, 4) void fattn_kernel(const bf16* __restrict__ qb,
                                                       const bf16* __restrict__ kb,
                                                       const bf16* __restrict__ vtb,
                                                       bf16* __restrict__ aop,
                                                       float* __restrict__ lpart) {
    const int id    = blockIdx.x;
    const int g     = id & 31;
    const int iblk  = id >> 5;           // 0..31
    const int bh    = g >> 2;
    const int split = g & 3;
    const int w     = threadIdx.x >> 6;
    const int lane  = threadIdx.x & 63;
    const int quad  = lane >> 4;
    const int li    = lane & 15;
    const int i0    = iblk * 128 + w * 32;
    const int j_lo  = split * 1024;

    const bf16* qrow = qb + (size_t)bh * NPOS * DHEAD;
    const bf16x8 qf0 = *(const bf16x8*)(qrow + (size_t)(i0 + li) * DHEAD + quad * 8);
    const bf16x8 qf1 = *(const bf16x8*)(qrow + (size_t)(i0 + 16 + li) * DHEAD + quad * 8);
    const bf16* kbase  = kb  + (size_t)bh * NPOS * DHEAD;
    const bf16* vtbase = vtb + (size_t)bh * DHEAD * NPOS;

    bf16x8 ones;
    #pragma unroll
    for (int j = 0; j < 8; ++j) ones[j] = (bf16)1.0f;

    f32x4 o00 = {0.f,0.f,0.f,0.f}, o01 = {0.f,0.f,0.f,0.f};
    f32x4 o10 = {0.f,0.f,0.f,0.f}, o11 = {0.f,0.f,0.f,0.f};
    f32x4 l0  = {0.f,0.f,0.f,0.f}, l1  = {0.f,0.f,0.f,0.f};

    __shared__ alignas(16) bf16 Kbuf[2][64][32];   // [buf][j_loc][d], 8 KB
    __shared__ alignas(16) bf16 Vbuf[2][32][64];   // [buf][d][j_loc], 8 KB (slot-swizzled)
    __shared__ alignas(16) bf16 plds[4][32][68];   // [wave][i][j], 17,408 B, wave-private

    const f32x4 zero = {0.f,0.f,0.f,0.f};

    // staging geometry: each wave stages 16 K-rows (1 KB) + 8 V-rows (1 KB)
    const int krow = w * 16 + (lane >> 2);        // 0..63 (j within tile)
    const int kcol = (lane & 3) * 8;              // d chunk (16 B)
    const int vrow = w * 8 + (lane >> 3);         // 0..31 (d)
    const int vchk = lane & 7;                    // j chunk (16 B)
    const int vslot = vchk ^ (vrow & 7);          // swizzled LDS slot
    const bf16* ksrc = kbase + (size_t)krow * DHEAD + kcol;
    const bf16* vsrc = vtbase + (size_t)vrow * NPOS + vchk * 8;

    bf16x8 kg, vg;

    // prologue: stage tile 0 into buf 0
    kg = *(const bf16x8*)(ksrc + (size_t)j_lo * DHEAD);
    vg = *(const bf16x8*)(vsrc + j_lo);
    *(bf16x8*)&Kbuf[0][krow][kcol]      = kg;
    *(bf16x8*)&Vbuf[0][vrow][vslot * 8] = vg;
    __syncthreads();

    for (int it = 0; it < 16; ++it) {
        const int cur = it & 1;
        const int j0  = j_lo + it * 64;
        // issue next tile's global loads (drain under this iteration's compute)
        if (it < 15) {
            kg = *(const bf16x8*)(ksrc + (size_t)(j0 + 64) * DHEAD);
            vg = *(const bf16x8*)(vsrc + j0 + 64);
        }
        // QK from Kbuf[cur]
        bf16x8 kf[4];
        #pragma unroll
        for (int tt = 0; tt < 4; ++tt)
            kf[tt] = *(const bf16x8*)&Kbuf[cur][16 * tt + li][quad * 8];
        f32x4 s0[4], s1[4];
        #pragma unroll
        for (int tt = 0; tt < 4; ++tt) {
            s0[tt] = __builtin_amdgcn_mfma_f32_16x16x32_bf16(kf[tt], qf0, zero, 0, 0, 0);
            s1[tt] = __builtin_amdgcn_mfma_f32_16x16x32_bf16(kf[tt], qf1, zero, 0, 0, 0);
        }
        // exp + pack + store into plds (wave-private; same-wave read below is ordered)
        #pragma unroll
        for (int tt = 0; tt < 4; ++tt) {
            bf16x4 p0, p1;
            #pragma unroll
            for (int r = 0; r < 4; ++r) {
                p0[r] = (bf16)__builtin_amdgcn_exp2f(s0[tt][r]);
                p1[r] = (bf16)__builtin_amdgcn_exp2f(s1[tt][r]);
            }
            *(bf16x4*)&plds[w][li][16 * tt + quad * 4]      = p0;
            *(bf16x4*)&plds[w][16 + li][16 * tt + quad * 4] = p1;
        }
        // PV (same tile) from plds + Vbuf[cur]
        #pragma unroll
        for (int h2 = 0; h2 < 2; ++h2) {
            B8 pf0, pf1;
            pf0.h[0] = *(const bf16x4*)&plds[w][li][h2 * 32 + quad * 8];
            pf0.h[1] = *(const bf16x4*)&plds[w][li][h2 * 32 + quad * 8 + 4];
            pf1.h[0] = *(const bf16x4*)&plds[w][16 + li][h2 * 32 + quad * 8];
            pf1.h[1] = *(const bf16x4*)&plds[w][16 + li][h2 * 32 + quad * 8 + 4];
            const int s0s = (h2 * 4 + quad) ^ (li & 7);   // read swizzle matches write
            bf16x8 v0f = *(const bf16x8*)&Vbuf[cur][li][s0s * 8];
            bf16x8 v1f = *(const bf16x8*)&Vbuf[cur][16 + li][s0s * 8];
            l0  = __builtin_amdgcn_mfma_f32_16x16x32_bf16(ones, pf0.v, l0,  0, 0, 0);
            l1  = __builtin_amdgcn_mfma_f32_16x16x32_bf16(ones, pf1.v, l1,  0, 0, 0);
            o00 = __builtin_amdgcn_mfma_f32_16x16x32_bf16(v0f,  pf0.v, o00, 0, 0, 0);
            o01 = __builtin_amdgcn_mfma_f32_16x16x32_bf16(v1f,  pf0.v, o01, 0, 0, 0);
            o10 = __builtin_amdgcn_mfma_f32_16x16x32_bf16(v0f,  pf1.v, o10, 0, 0, 0);
            o11 = __builtin_amdgcn_mfma_f32_16x16x32_bf16(v1f,  pf1.v, o11, 0, 0, 0);
        }
        // stage next tile into the other buffer (its readers are past the barrier)
        if (it < 15) {
            *(bf16x8*)&Kbuf[cur ^ 1][krow][kcol]      = kg;
            *(bf16x8*)&Vbuf[cur ^ 1][vrow][vslot * 8] = vg;
        }
        __syncthreads();
    }

    const int b = bh >> 2, h = bh & 3;
    {
        const int i = i0 + li;
        bf16* dst = aop + (((size_t)(split * NB + b) * NPOS + i) * HID) + h * DHEAD;
        bf16x4 pk0, pk1;
        #pragma unroll
        for (int r = 0; r < 4; ++r) { pk0[r] = (bf16)o00[r]; pk1[r] = (bf16)o01[r]; }
        *(bf16x4*)(dst + quad * 4)      = pk0;
        *(bf16x4*)(dst + 16 + quad * 4) = pk1;
        if (quad == 0) lpart[((size_t)split * NBH + bh) * NPOS + i] = l0[0];
    }
    {
        const int i = i0 + 16 + li;
        bf16* dst = aop + (((size_t)(split * NB + b) * NPOS + i) * HID) + h * DHEAD;
        bf16x4 pk0, pk1;
        #pragma unroll
        for (int r = 0; r < 4; ++r) { pk0[r] = (bf16)o10[r]; pk1[r] = (bf16)o11[r]; }
        *(bf16x4*)(dst + quad * 4)      = pk0;
        *(bf16x4*)(dst + 16 + quad * 4) = pk1;
        if (quad == 0) lpart[((size_t)split * NBH + bh) * NPOS + i] = l1[0];
    }
}

// ---------------- Kernel 3: proj GEMM — combine ONCE per row (ot fused) ----------------
// R15: old grid (64i, 4ot, 2b) recombined the same rows 4x (aop 32 MB reads, 4x
// combine VALU). New: 16-row i-tiles, all 256 outputs per block — grid (256, 2) =
// 512 blocks (2/CU unchanged). Combine once (aop 8 MB, VALU /4); wave w owns
// outputs [w*64, w*64+64): 4 o-frags x 4 k-steps = 16 MFMAs/wave (total unchanged).
// Cost: wob re-read 64 KB/block (L2-resident, +~1 us). Coalescing: 16 consecutive
// threads read 256 B contiguous aop.
__global__ __launch_bounds__(256) void proj_kernel(const bf16* __restrict__ aop,
                                                   const float* __restrict__ lpart,
                                                   const bf16* __restrict__ wob,
                                                   const float* __restrict__ bout,
                                                   float* __restrict__ y) {
    const int i0 = blockIdx.x * 16;
    const int b  = blockIdx.y;
    const int t  = threadIdx.x;
    const int w  = t >> 6;
    const int lane = t & 63;
    const int quad = lane >> 4;
    const int li   = lane & 15;

    __shared__ bf16 Bs[16][132];   // [i_loc][c], 4.2 KB

    // staging with combine: thread = (row, 8-channel chunk); each row combined ONCE
    {
        const int row = t >> 4;          // 0..15
        const int cp  = (t & 15) * 8;    // 0..120
        const int gi  = i0 + row;
        const int h   = cp >> 5;

        float lsum = 0.f;
        #pragma unroll
        for (int s = 0; s < NSPLIT; ++s)
            lsum += lpart[((size_t)s * NBH + b * NHEAD + h) * NPOS + gi];
        const float invl = __builtin_amdgcn_rcpf(lsum);

        float vals[8];
        #pragma unroll
        for (int j = 0; j < 8; ++j) vals[j] = 0.f;
        #pragma unroll
        for (int s = 0; s < NSPLIT; ++s) {
            bf16x8 u = *(const bf16x8*)(aop + (((size_t)(s * NB + b) * NPOS + gi) * HID) + cp);
            #pragma unroll
            for (int j = 0; j < 8; ++j) vals[j] += (float)u[j];
        }
        B8 pk;
        #pragma unroll
        for (int j = 0; j < 8; ++j) pk.v[j] = (bf16)(vals[j] * invl);
        *(bf16x4*)&Bs[row][cp]     = pk.h[0];
        *(bf16x4*)&Bs[row][cp + 4] = pk.h[1];
    }
    __syncthreads();

    f32x4 acc[4];
    #pragma unroll
    for (int m = 0; m < 4; ++m) acc[m] = (f32x4){0.f, 0.f, 0.f, 0.f};

    #pragma unroll
    for (int k0 = 0; k0 < HID; k0 += 32) {
        B8 bf;
        bf.h[0] = *(const bf16x4*)&Bs[li][k0 + quad * 8];
        bf.h[1] = *(const bf16x4*)&Bs[li][k0 + quad * 8 + 4];
        #pragma unroll
        for (int m = 0; m < 4; ++m) {
            bf16x8 afrag = *(const bf16x8*)(wob + (size_t)(w * 64 + m * 16 + li) * HID + k0 + quad * 8);
            acc[m] = __builtin_amdgcn_mfma_f32_16x16x32_bf16(afrag, bf.v, acc[m], 0, 0, 0);
        }
    }

    float* yb = y + (size_t)b * CIN * NPOS;
    #pragma unroll
    for (int m = 0; m < 4; ++m) {
        const int oc = w * 64 + m * 16 + quad * 4;
        #pragma unroll
        for (int r = 0; r < 4; ++r)
            yb[(size_t)(oc + r) * NPOS + i0 + li] = acc[m][r] + bout[oc + r];
    }
}

extern "C" void kernel_launch(void* const* d_in, const int* in_sizes, int n_in,
                              void* d_out, int out_size, void* d_ws, size_t ws_size,
                              hipStream_t stream) {
    const float* x    = (const float*)d_in[0];
    const float* wqkv = (const float*)d_in[1];
    const float* wout = (const float*)d_in[2];
    const float* bout = (const float*)d_in[3];
    float* y = (float*)d_out;
    char* ws = (char*)d_ws;

    bf16*  xt  = (bf16*)(ws + XT_OFF);
    bf16*  qb  = (bf16*)(ws + QB_OFF);
    bf16*  kb  = (bf16*)(ws + KB_OFF);
    bf16*  vtb = (bf16*)(ws + VT_OFF);
    bf16*  aop = (bf16*)(ws + AOP_OFF);
    float* lp  = (float*)(ws + LP_OFF);
    bf16*  wb  = (bf16*)(ws + WB_OFF);
    bf16*  wob = (bf16*)(ws + WOB_OFF);

    prep_kernel<<<dim3(64, 5, 2), 256, 0, stream>>>(x, wqkv, wout, xt, wb, wob);
    qkv_kernel<<<dim3(64, 6, 2), 256, 0, stream>>>(xt, wb, qb, kb, vtb);
    fattn_kernel<<<dim3(1024), 256, 0, stream>>>(qb, kb, vtb, aop, lp);
    proj_kernel<<<dim3(256, 2), 256, 0, stream>>>(aop, lp, wob, bout, y);
}

// Round 11
// 103.029 us; speedup vs baseline: 1.6466x; 1.0471x over previous
//
#include <hip/hip_runtime.h>
#include <hip/hip_bf16.h>
#include <math.h>

#define NB 2
#define CIN 256
#define NPOS 4096          // 64*64
#define HID 128
#define NHEAD 4
#define DHEAD 32
#define NBH 8
#define NSPLIT 4
#define QSCALE 0.2550348676144781f   // 32^-0.5 * log2(e), folded into W_q

typedef __bf16 bf16;
typedef __attribute__((ext_vector_type(8))) __bf16 bf16x8;
typedef __attribute__((ext_vector_type(4))) __bf16 bf16x4;
typedef __attribute__((ext_vector_type(4))) float f32x4;

union B8 { bf16x8 v; bf16x4 h[2]; };

// ws layout (byte offsets), total 19,660,800 B (R0/R11 layout):
#define XT_OFF  0u            // xt  bf16 [2][4096][256]   4 MB
#define QB_OFF  4194304u      // qb  bf16 [8][4096][32]    2 MB  (W_q pre-scaled by QSCALE)
#define KB_OFF  6291456u      // kb  bf16 [8][4096][32]    2 MB
#define VT_OFF  8388608u      // vtb bf16 [8][32][4096]    2 MB  (V transposed, j-PERMUTED per 64-block)
#define AOP_OFF 10485760u     // aop bf16 [4][2][4096][128] 8 MB (partial O, [split][b][i][c])
#define LP_OFF  18874368u     // lp  f32  [4][8][4096]     512 KB
#define WB_OFF  19398656u     // wb  bf16 [384][256]       192 KB
#define WOB_OFF 19595264u     // wob bf16 [256][128]       64 KB

// ---------------- Kernel 0: prep — transpose x to bf16 [b][i][c]; cast weights (R15 verbatim) ----------------
__global__ __launch_bounds__(256) void prep_kernel(const float* __restrict__ x,
                                                   const float* __restrict__ wqkv,
                                                   const float* __restrict__ wout,
                                                   bf16* __restrict__ xt,
                                                   bf16* __restrict__ wb,
                                                   bf16* __restrict__ wob) {
    const int t = threadIdx.x;
    if (blockIdx.y == 4) {
        int tid = blockIdx.x * 256 + t;           // 0..16383
        if (blockIdx.z == 0) {
            #pragma unroll
            for (int u = 0; u < 6; ++u) {
                int idx = tid * 6 + u;            // 98304 = 384*256 exactly
                float v = wqkv[idx];
                if (idx < 32768) v *= QSCALE;     // rows 0..127 = W_q
                wb[idx] = (bf16)v;
            }
        } else {
            wob[tid * 2]     = (bf16)wout[tid * 2];     // 32768 = 256*128
            wob[tid * 2 + 1] = (bf16)wout[tid * 2 + 1];
        }
        return;
    }
    const int b  = blockIdx.z;
    const int c0 = blockIdx.y * 64;
    const int i0 = blockIdx.x * 64;
    __shared__ float Ts[64][65];
    const float* xb = x + (size_t)b * CIN * NPOS;
    #pragma unroll
    for (int u = 0; u < 4; ++u) {
        int c = (t >> 4) + u * 16;
        int i = (t & 15) * 4;
        float4 v = *(const float4*)(xb + (size_t)(c0 + c) * NPOS + i0 + i);
        Ts[c][i] = v.x; Ts[c][i + 1] = v.y; Ts[c][i + 2] = v.z; Ts[c][i + 3] = v.w;
    }
    __syncthreads();
    int i  = t & 63;
    int cc = (t >> 6) * 16;
    B8 o0, o1;
    #pragma unroll
    for (int j = 0; j < 8; ++j) {
        o0.v[j] = (bf16)Ts[cc + j][i];
        o1.v[j] = (bf16)Ts[cc + 8 + j][i];
    }
    bf16* dst = xt + ((size_t)b * NPOS + i0 + i) * CIN + c0 + cc;
    *(bf16x8*)dst       = o0.v;
    *(bf16x8*)(dst + 8) = o1.v;
}

// ---------------- Kernel 1: qkv MFMA GEMM — vtb written j-PERMUTED (R16) ----------------
// R16: vtb columns are remapped within each 64-block by k(m) = 32*(n>>1) + 8*(li>>2)
// + 4*(n&1) + (li&3)  (m = n*16+li). This makes fattn's PV B-operand layout equal
// QK's C/D register layout (j is a reduction axis: permuting j is legal iff V is
// permuted identically) — eliminating fattn's plds P round-trip entirely.
__global__ __launch_bounds__(256) void qkv_kernel(const bf16* __restrict__ xt,
                                                  const bf16* __restrict__ wb,
                                                  bf16* __restrict__ qb,
                                                  bf16* __restrict__ kb,
                                                  bf16* __restrict__ vtb) {
    const int i0 = blockIdx.x * 64;
    const int ot = blockIdx.y * 64;
    const int b  = blockIdx.z;
    const int t  = threadIdx.x;
    const int w  = t >> 6;
    const int lane = t & 63;
    const int quad = lane >> 4;
    const int li   = lane & 15;

    __shared__ bf16 Bs[64][36];   // [i_loc][k]

    f32x4 acc[4];
    #pragma unroll
    for (int n = 0; n < 4; ++n) acc[n] = (f32x4){0.f, 0.f, 0.f, 0.f};

    const bf16* xrow = xt + ((size_t)b * NPOS + i0) * CIN;
    const int si = t >> 2;            // 0..63
    const int sk = (t & 3) * 8;       // 0,8,16,24

    for (int k0 = 0; k0 < CIN; k0 += 32) {
        __syncthreads();
        B8 g0;
        g0.v = *(const bf16x8*)(xrow + (size_t)si * CIN + k0 + sk);
        *(bf16x4*)&Bs[si][sk]     = g0.h[0];
        *(bf16x4*)&Bs[si][sk + 4] = g0.h[1];
        __syncthreads();
        bf16x8 afrag = *(const bf16x8*)(wb + (size_t)(ot + w * 16 + li) * CIN + k0 + quad * 8);
        #pragma unroll
        for (int n = 0; n < 4; ++n) {
            B8 bf;
            bf.h[0] = *(const bf16x4*)&Bs[n * 16 + li][quad * 8];
            bf.h[1] = *(const bf16x4*)&Bs[n * 16 + li][quad * 8 + 4];
            acc[n] = __builtin_amdgcn_mfma_f32_16x16x32_bf16(afrag, bf.v, acc[n], 0, 0, 0);
        }
    }

    const int obase = ot + w * 16;
    const int sect  = obase >> 7;            // 0=q 1=k 2=v
    const int oo    = obase & 127;
    const int h     = oo >> 5;
    const int dbase = (oo & 31) + quad * 4;
    const int bh    = b * NHEAD + h;

    #pragma unroll
    for (int n = 0; n < 4; ++n) {
        int i = i0 + n * 16 + li;
        f32x4 v = acc[n];
        if (sect <= 1) {
            bf16x4 pk;
            #pragma unroll
            for (int r = 0; r < 4; ++r) pk[r] = (bf16)v[r];
            bf16* base = (sect == 0) ? qb : kb;
            *(bf16x4*)(base + ((size_t)bh * NPOS + i) * DHEAD + dbase) = pk;
        } else {
            // j-permuted V column: i0 + k(m), m = n*16 + li
            const int ip = i0 + ((n >> 1) << 5) + ((li >> 2) << 3) + ((n & 1) << 2) + (li & 3);
            #pragma unroll
            for (int r = 0; r < 4; ++r)
                vtb[((size_t)bh * DHEAD + dbase + r) * NPOS + ip] = (bf16)v[r];
        }
    }
}

// ---------------- Kernel 2: MFMA flash attention — P stays in registers (R16) ----------------
// R14 structure is LDS-throughput bound: 26 DS ops/wave/iter (16 of them the plds
// P round-trip). With the vtb j-permutation, QK's C/D output IS PV's B-operand:
// pf_h2 = pack(exp(s[2h2][0..3]), exp(s[2h2+1][0..3])) straight from registers.
// plds deleted: 10 DS ops/wave/iter, LDS 33.4 -> 16 KB, ~150cy LDS latency leaves
// the chain. K staging, V swizzle, epilogue byte-identical to R14/R15.
__global__ __launch_bounds__(256, 4) void fattn_kernel(const bf16* __restrict__ qb,
                                                       const bf16* __restrict__ kb,
                                                       const bf16* __restrict__ vtb,
                                                       bf16* __restrict__ aop,
                                                       float* __restrict__ lpart) {
    const int id    = blockIdx.x;
    const int g     = id & 31;
    const int iblk  = id >> 5;           // 0..31
    const int bh    = g >> 2;
    const int split = g & 3;
    const int w     = threadIdx.x >> 6;
    const int lane  = threadIdx.x & 63;
    const int quad  = lane >> 4;
    const int li    = lane & 15;
    const int i0    = iblk * 128 + w * 32;
    const int j_lo  = split * 1024;

    const bf16* qrow = qb + (size_t)bh * NPOS * DHEAD;
    const bf16x8 qf0 = *(const bf16x8*)(qrow + (size_t)(i0 + li) * DHEAD + quad * 8);
    const bf16x8 qf1 = *(const bf16x8*)(qrow + (size_t)(i0 + 16 + li) * DHEAD + quad * 8);
    const bf16* kbase  = kb  + (size_t)bh * NPOS * DHEAD;
    const bf16* vtbase = vtb + (size_t)bh * DHEAD * NPOS;

    bf16x8 ones;
    #pragma unroll
    for (int j = 0; j < 8; ++j) ones[j] = (bf16)1.0f;

    f32x4 o00 = {0.f,0.f,0.f,0.f}, o01 = {0.f,0.f,0.f,0.f};
    f32x4 o10 = {0.f,0.f,0.f,0.f}, o11 = {0.f,0.f,0.f,0.f};
    f32x4 l0  = {0.f,0.f,0.f,0.f}, l1  = {0.f,0.f,0.f,0.f};

    __shared__ alignas(16) bf16 Kbuf[2][64][32];   // [buf][j_loc][d], 8 KB
    __shared__ alignas(16) bf16 Vbuf[2][32][64];   // [buf][d][k_slot], 8 KB (slot-swizzled)

    const f32x4 zero = {0.f,0.f,0.f,0.f};

    // staging geometry: each wave stages 16 K-rows (1 KB) + 8 V-rows (1 KB)
    const int krow = w * 16 + (lane >> 2);        // 0..63 (j within tile)
    const int kcol = (lane & 3) * 8;              // d chunk (16 B)
    const int vrow = w * 8 + (lane >> 3);         // 0..31 (d)
    const int vchk = lane & 7;                    // k chunk (16 B)
    const int vslot = vchk ^ (vrow & 7);          // swizzled LDS slot
    const bf16* ksrc = kbase + (size_t)krow * DHEAD + kcol;
    const bf16* vsrc = vtbase + (size_t)vrow * NPOS + vchk * 8;

    bf16x8 kg, vg;

    // prologue: stage tile 0 into buf 0
    kg = *(const bf16x8*)(ksrc + (size_t)j_lo * DHEAD);
    vg = *(const bf16x8*)(vsrc + j_lo);
    *(bf16x8*)&Kbuf[0][krow][kcol]      = kg;
    *(bf16x8*)&Vbuf[0][vrow][vslot * 8] = vg;
    __syncthreads();

    for (int it = 0; it < 16; ++it) {
        const int cur = it & 1;
        const int j0  = j_lo + it * 64;
        // issue next tile's global loads (drain under this iteration's compute)
        if (it < 15) {
            kg = *(const bf16x8*)(ksrc + (size_t)(j0 + 64) * DHEAD);
            vg = *(const bf16x8*)(vsrc + j0 + 64);
        }
        // QK from Kbuf[cur]
        bf16x8 kf[4];
        #pragma unroll
        for (int tt = 0; tt < 4; ++tt)
            kf[tt] = *(const bf16x8*)&Kbuf[cur][16 * tt + li][quad * 8];
        f32x4 s0[4], s1[4];
        #pragma unroll
        for (int tt = 0; tt < 4; ++tt) {
            s0[tt] = __builtin_amdgcn_mfma_f32_16x16x32_bf16(kf[tt], qf0, zero, 0, 0, 0);
            s1[tt] = __builtin_amdgcn_mfma_f32_16x16x32_bf16(kf[tt], qf1, zero, 0, 0, 0);
        }
        // exp in-register -> PV B-fragments directly (k(m) permutation pre-applied to V)
        #pragma unroll
        for (int h2 = 0; h2 < 2; ++h2) {
            B8 pa0, pa1;
            #pragma unroll
            for (int r = 0; r < 4; ++r) {
                pa0.v[r]     = (bf16)__builtin_amdgcn_exp2f(s0[2 * h2][r]);
                pa0.v[4 + r] = (bf16)__builtin_amdgcn_exp2f(s0[2 * h2 + 1][r]);
                pa1.v[r]     = (bf16)__builtin_amdgcn_exp2f(s1[2 * h2][r]);
                pa1.v[4 + r] = (bf16)__builtin_amdgcn_exp2f(s1[2 * h2 + 1][r]);
            }
            const int s0s = (h2 * 4 + quad) ^ (li & 7);   // read swizzle matches write
            bf16x8 v0f = *(const bf16x8*)&Vbuf[cur][li][s0s * 8];
            bf16x8 v1f = *(const bf16x8*)&Vbuf[cur][16 + li][s0s * 8];
            l0  = __builtin_amdgcn_mfma_f32_16x16x32_bf16(ones, pa0.v, l0,  0, 0, 0);
            l1  = __builtin_amdgcn_mfma_f32_16x16x32_bf16(ones, pa1.v, l1,  0, 0, 0);
            o00 = __builtin_amdgcn_mfma_f32_16x16x32_bf16(v0f,  pa0.v, o00, 0, 0, 0);
            o01 = __builtin_amdgcn_mfma_f32_16x16x32_bf16(v1f,  pa0.v, o01, 0, 0, 0);
            o10 = __builtin_amdgcn_mfma_f32_16x16x32_bf16(v0f,  pa1.v, o10, 0, 0, 0);
            o11 = __builtin_amdgcn_mfma_f32_16x16x32_bf16(v1f,  pa1.v, o11, 0, 0, 0);
        }
        // stage next tile into the other buffer (its readers are past the barrier)
        if (it < 15) {
            *(bf16x8*)&Kbuf[cur ^ 1][krow][kcol]      = kg;
            *(bf16x8*)&Vbuf[cur ^ 1][vrow][vslot * 8] = vg;
        }
        __syncthreads();
    }

    const int b = bh >> 2, h = bh & 3;
    {
        const int i = i0 + li;
        bf16* dst = aop + (((size_t)(split * NB + b) * NPOS + i) * HID) + h * DHEAD;
        bf16x4 pk0, pk1;
        #pragma unroll
        for (int r = 0; r < 4; ++r) { pk0[r] = (bf16)o00[r]; pk1[r] = (bf16)o01[r]; }
        *(bf16x4*)(dst + quad * 4)      = pk0;
        *(bf16x4*)(dst + 16 + quad * 4) = pk1;
        if (quad == 0) lpart[((size_t)split * NBH + bh) * NPOS + i] = l0[0];
    }
    {
        const int i = i0 + 16 + li;
        bf16* dst = aop + (((size_t)(split * NB + b) * NPOS + i) * HID) + h * DHEAD;
        bf16x4 pk0, pk1;
        #pragma unroll
        for (int r = 0; r < 4; ++r) { pk0[r] = (bf16)o10[r]; pk1[r] = (bf16)o11[r]; }
        *(bf16x4*)(dst + quad * 4)      = pk0;
        *(bf16x4*)(dst + 16 + quad * 4) = pk1;
        if (quad == 0) lpart[((size_t)split * NBH + bh) * NPOS + i] = l1[0];
    }
}

// ---------------- Kernel 3: proj GEMM — combine ONCE per row (R15 verbatim) ----------------
__global__ __launch_bounds__(256) void proj_kernel(const bf16* __restrict__ aop,
                                                   const float* __restrict__ lpart,
                                                   const bf16* __restrict__ wob,
                                                   const float* __restrict__ bout,
                                                   float* __restrict__ y) {
    const int i0 = blockIdx.x * 16;
    const int b  = blockIdx.y;
    const int t  = threadIdx.x;
    const int w  = t >> 6;
    const int lane = t & 63;
    const int quad = lane >> 4;
    const int li   = lane & 15;

    __shared__ bf16 Bs[16][132];   // [i_loc][c], 4.2 KB

    // staging with combine: thread = (row, 8-channel chunk); each row combined ONCE
    {
        const int row = t >> 4;          // 0..15
        const int cp  = (t & 15) * 8;    // 0..120
        const int gi  = i0 + row;
        const int h   = cp >> 5;

        float lsum = 0.f;
        #pragma unroll
        for (int s = 0; s < NSPLIT; ++s)
            lsum += lpart[((size_t)s * NBH + b * NHEAD + h) * NPOS + gi];
        const float invl = __builtin_amdgcn_rcpf(lsum);

        float vals[8];
        #pragma unroll
        for (int j = 0; j < 8; ++j) vals[j] = 0.f;
        #pragma unroll
        for (int s = 0; s < NSPLIT; ++s) {
            bf16x8 u = *(const bf16x8*)(aop + (((size_t)(s * NB + b) * NPOS + gi) * HID) + cp);
            #pragma unroll
            for (int j = 0; j < 8; ++j) vals[j] += (float)u[j];
        }
        B8 pk;
        #pragma unroll
        for (int j = 0; j < 8; ++j) pk.v[j] = (bf16)(vals[j] * invl);
        *(bf16x4*)&Bs[row][cp]     = pk.h[0];
        *(bf16x4*)&Bs[row][cp + 4] = pk.h[1];
    }
    __syncthreads();

    f32x4 acc[4];
    #pragma unroll
    for (int m = 0; m < 4; ++m) acc[m] = (f32x4){0.f, 0.f, 0.f, 0.f};

    #pragma unroll
    for (int k0 = 0; k0 < HID; k0 += 32) {
        B8 bf;
        bf.h[0] = *(const bf16x4*)&Bs[li][k0 + quad * 8];
        bf.h[1] = *(const bf16x4*)&Bs[li][k0 + quad * 8 + 4];
        #pragma unroll
        for (int m = 0; m < 4; ++m) {
            bf16x8 afrag = *(const bf16x8*)(wob + (size_t)(w * 64 + m * 16 + li) * HID + k0 + quad * 8);
            acc[m] = __builtin_amdgcn_mfma_f32_16x16x32_bf16(afrag, bf.v, acc[m], 0, 0, 0);
        }
    }

    float* yb = y + (size_t)b * CIN * NPOS;
    #pragma unroll
    for (int m = 0; m < 4; ++m) {
        const int oc = w * 64 + m * 16 + quad * 4;
        #pragma unroll
        for (int r = 0; r < 4; ++r)
            yb[(size_t)(oc + r) * NPOS + i0 + li] = acc[m][r] + bout[oc + r];
    }
}

extern "C" void kernel_launch(void* const* d_in, const int* in_sizes, int n_in,
                              void* d_out, int out_size, void* d_ws, size_t ws_size,
                              hipStream_t stream) {
    const float* x    = (const float*)d_in[0];
    const float* wqkv = (const float*)d_in[1];
    const float* wout = (const float*)d_in[2];
    const float* bout = (const float*)d_in[3];
    float* y = (float*)d_out;
    char* ws = (char*)d_ws;

    bf16*  xt  = (bf16*)(ws + XT_OFF);
    bf16*  qb  = (bf16*)(ws + QB_OFF);
    bf16*  kb  = (bf16*)(ws + KB_OFF);
    bf16*  vtb = (bf16*)(ws + VT_OFF);
    bf16*  aop = (bf16*)(ws + AOP_OFF);
    float* lp  = (float*)(ws + LP_OFF);
    bf16*  wb  = (bf16*)(ws + WB_OFF);
    bf16*  wob = (bf16*)(ws + WOB_OFF);

    prep_kernel<<<dim3(64, 5, 2), 256, 0, stream>>>(x, wqkv, wout, xt, wb, wob);
    qkv_kernel<<<dim3(64, 6, 2), 256, 0, stream>>>(xt, wb, qb, kb, vtb);
    fattn_kernel<<<dim3(1024), 256, 0, stream>>>(qb, kb, vtb, aop, lp);
    proj_kernel<<<dim3(256, 2), 256, 0, stream>>>(aop, lp, wob, bout, y);
}